// Round 1
// baseline (2361.565 us; speedup 1.0000x reference)
//
#include <hip/hip_runtime.h>
#include <hip/hip_bf16.h>
#include <cstdint>
#include <cstddef>

// Problem constants
#define H_    128
#define IN_   86
#define OUT_  66
#define T_    50
#define B_    8192
#define NPOSE 15

// Round-6 design: phase fusion + cross-barrier load issue + nt cache hints.
//  - Key dependency fact: gates1(t) and gates0(t+1) both need only h1(t)
//    (+ h2(t-1) / x(t+1)) and are independent of each other -> fuse into ONE
//    GEMM phase. Main loop (t=0..49): 2 barriers/timestep instead of 5-6.
//  - Tail (t=50..64, pose feedback): gates0(t+1) k-tiles 3..6 depend only on
//    h1(t) -> hoisted into the gates1 phase; only k=0..2 (pose|cond) run after
//    the dense head. 4 barriers/step instead of 6.
//  - All global loads (B-frag k=0 prefetch, x staging) are ISSUED at the top
//    of the pointwise phase so the compiler's vmcnt(0) drain at the barrier
//    is covered by pointwise VALU work.
//  - x loads / out stores are non-temporal so the 512KB packed-weight set
//    stays L2-resident (FETCH_SIZE showed ~2.6GB of weight re-fetch).
//  - Same tiling as round-5: BR=16, grid 512 (2 blocks/CU), 8 waves/block,
//    wave w owns unit slice w*16..w*16+15 across all 4 gates; hi-only bf16
//    weights, hi/lo split activations (2 MFMAs/frag). Numerics unchanged.
// K0 = 224: [u(86)|pad(10)|h1(128)] ; K1 = 256: [h1|h2]
#define K0T 7
#define K1T 8
#define KDT 4
#define NT0 32
#define NT1 32
#define NTD 5
#define S0  232   // A0 row stride (ushorts); 116 dwords = 4*odd (2-way, free)
#define S1  264   // A1 row stride; 132 dwords = 4*odd
#define BR  16

// ws layout (bytes) — hi-only packed B fragments
#define B0P_OFF 0
#define B0P_SZ  (K0T * NT0 * 1024)       // 229376
#define B1P_OFF (B0P_OFF + B0P_SZ)
#define B1P_SZ  (K1T * NT1 * 1024)       // 262144
#define BDP_OFF (B1P_OFF + B1P_SZ)       // 491520
#define BDP_SZ  (KDT * NTD * 1024)       // 20480
#define B0P_N (B0P_SZ / 2)               // 114688
#define B1P_N (B1P_SZ / 2)               // 131072
#define TOT_N ((B0P_SZ + B1P_SZ + BDP_SZ) / 2)   // 256000

typedef __attribute__((ext_vector_type(8))) short bfrag;
typedef __attribute__((ext_vector_type(4))) float ffrag;

#define MFMA(AC, AA, BB) \
  AC = __builtin_amdgcn_mfma_f32_16x16x32_bf16((AA), (BB), (AC), 0, 0, 0)

__device__ __forceinline__ unsigned short bf16rn(float f) {
  union { float f; unsigned int u; } cv; cv.f = f;
  unsigned int u = cv.u;
  u += 0x7FFFu + ((u >> 16) & 1u);   // round-to-nearest-even
  return (unsigned short)(u >> 16);
}
__device__ __forceinline__ float bf16tof(unsigned short h) {
  union { unsigned int u; float f; } cv; cv.u = ((unsigned int)h) << 16;
  return cv.f;
}
__device__ __forceinline__ float sigmoid_f(float v) {
  return __fdividef(1.f, 1.f + __expf(-v));
}
__device__ __forceinline__ float tanh_f(float v) {
  float av = fabsf(v);
  float e  = __expf(-2.f * av);
  float t  = __fdividef(1.f - e, 1.f + e);
  return copysignf(t, v);
}

// ---------------- prep: pack hi-only weights in MFMA fragment order ---------
__global__ void wm_prep(
    const float* __restrict__ Wih0, const float* __restrict__ Whh0,
    const float* __restrict__ Wih1, const float* __restrict__ Whh1,
    const float* __restrict__ Wd,
    unsigned short* __restrict__ wsu)
{
  const int idx = blockIdx.x * 256 + threadIdx.x;
  if (idx >= TOT_N) return;
  int region, l;
  if (idx < B0P_N)               { region = 0; l = idx; }
  else if (idx < B0P_N + B1P_N)  { region = 1; l = idx - B0P_N; }
  else                           { region = 2; l = idx - (B0P_N + B1P_N); }

  int k, nt, lane, j;
  if (region < 2) {
    k  = l >> 14;            // 32 tiles * 512 ushorts = 16384 per ktile
    int r1 = l & 16383;
    nt = r1 >> 9;
    int li = r1 & 511;
    lane = li >> 3; j = li & 7;
  } else {
    k  = l / 2560;           // 5 * 512 per ktile
    int r1 = l % 2560;
    nt = r1 >> 9;
    int li = r1 & 511;
    lane = li >> 3; j = li & 7;
  }
  const int n  = nt * 16 + (lane & 15);
  const int kk = k * 32 + (lane >> 4) * 8 + j;

  float v = 0.f;
  if (region == 0) {
    if (kk < IN_)                    v = Wih0[n * IN_ + kk];
    else if (kk >= 96 && kk < 224)   v = Whh0[n * H_ + (kk - 96)];
  } else if (region == 1) {
    v = (kk < H_) ? Wih1[n * H_ + kk] : Whh1[n * H_ + (kk - H_)];
  } else {
    if (n < OUT_)                    v = Wd[n * H_ + kk];
  }
  wsu[idx] = bf16rn(v);
}

// ---------------- GEMM helpers ----------------------------------------------
__device__ __forceinline__ void load_bk(const char* __restrict__ Bb, int k, int NT,
                                        int wv, int lane16, bfrag pb[4]) {
  #pragma unroll
  for (int g = 0; g < 4; ++g)
    pb[g] = *(const bfrag*)(Bb + (size_t)(k * NT + g * 8 + wv) * 1024 + lane16);
}

// K-tile segment [KF, KL); first k-tile's B-frags come prefetched in pb.
template<int KF, int KL>
__device__ __forceinline__ void gemm_seg(const unsigned short* Ah, const unsigned short* Al,
                                         int ab, const char* __restrict__ Bb, int NT,
                                         int wv, int lane16, const bfrag pb[4],
                                         ffrag acc[4]) {
  {
    const bfrag ah = *(const bfrag*)(Ah + ab + KF * 32);
    const bfrag al = *(const bfrag*)(Al + ab + KF * 32);
    #pragma unroll
    for (int g = 0; g < 4; ++g) { MFMA(acc[g], ah, pb[g]); MFMA(acc[g], al, pb[g]); }
  }
  #pragma unroll 2
  for (int k = KF + 1; k < KL; ++k) {
    const bfrag ah = *(const bfrag*)(Ah + ab + k * 32);
    const bfrag al = *(const bfrag*)(Al + ab + k * 32);
    #pragma unroll
    for (int g = 0; g < 4; ++g) {
      const bfrag bh = *(const bfrag*)(Bb + (size_t)(k * NT + g * 8 + wv) * 1024 + lane16);
      MFMA(acc[g], ah, bh);
      MFMA(acc[g], al, bh);
    }
  }
}

// ---------------- main persistent-recurrence kernel --------------------------
__global__ __launch_bounds__(512, 4) void wm_main(
    const float* __restrict__ x,
    const char*  __restrict__ wsb,
    const float* __restrict__ bih0, const float* __restrict__ bhh0,
    const float* __restrict__ bih1, const float* __restrict__ bhh1,
    const float* __restrict__ bd,
    float* __restrict__ out)
{
  __shared__ __align__(16) unsigned short A0h[BR * S0];
  __shared__ __align__(16) unsigned short A0l[BR * S0];
  __shared__ __align__(16) unsigned short A1h[BR * S1];
  __shared__ __align__(16) unsigned short A1l[BR * S1];

  const int tid  = threadIdx.x;
  const int lane = tid & 63;
  const int wv   = tid >> 6;      // wave id = unit-slice id (0..7)
  const int ln15 = lane & 15;
  const int quad = lane >> 4;
  const int lane16 = lane * 16;

  const char* B0 = wsb + B0P_OFF;
  const char* B1 = wsb + B1P_OFF;
  const char* BD = wsb + BDP_OFF;

  // zero LDS (h/c zero-init; A0 pads [86,96) and [224,232) stay zero)
  for (int i = tid; i < BR * S0; i += 512) { A0h[i] = 0; A0l[i] = 0; }
  for (int i = tid; i < BR * S1; i += 512) { A1h[i] = 0; A1l[i] = 0; }

  // bias preload — this wave's unit col = wv*16 + ln15, per gate g
  float b0r[4], b1r[4];
  #pragma unroll
  for (int g = 0; g < 4; ++g) {
    const int n = g * 128 + wv * 16 + ln15;
    b0r[g] = bih0[n] + bhh0[n];
    b1r[g] = bih1[n] + bhh1[n];
  }
  // dense head: waves 0..4 own o-tile wv (o = wv*16 + ln15)
  const int od = wv * 16 + ln15;
  const float bdr = (wv < NTD && od < OUT_) ? bd[od] : 0.f;

  float c1[4], c2[4];
  #pragma unroll
  for (int r = 0; r < 4; ++r) { c1[r] = 0.f; c2[r] = 0.f; }

  const int a0b = ln15 * S0 + quad * 8;    // A-frag offset (row ln15)
  const int a1b = ln15 * S1 + quad * 8;
  const int prow = quad * 4;               // C/D rows = prow + r
  const int unit = wv * 16 + ln15;         // this lane's unit column
  const int xr_row = tid >> 5;             // staging: 16 rows x 32 lanes
  const int xr_col = tid & 31;

  // pointwise lambdas ---------------------------------------------------------
  auto pw_l1 = [&](const ffrag a4[4]) {    // h1 from acc0; writes A0[96+], A1[0+]
    #pragma unroll
    for (int rr = 0; rr < 4; ++rr) {
      const float ig = sigmoid_f(a4[0][rr]);
      const float fg = sigmoid_f(a4[1][rr]);
      const float gg = tanh_f(a4[2][rr]);
      const float og = sigmoid_f(a4[3][rr]);
      const float c  = fmaf(fg, c1[rr], ig * gg);
      c1[rr] = c;
      const float h  = og * tanh_f(c);
      const unsigned short hi = bf16rn(h);
      const unsigned short lo = bf16rn(h - bf16tof(hi));
      const int row = prow + rr;
      A0h[row * S0 + 96 + unit] = hi;  A0l[row * S0 + 96 + unit] = lo;
      A1h[row * S1 + unit]      = hi;  A1l[row * S1 + unit]      = lo;
    }
  };
  auto pw_l2 = [&](const ffrag a4[4]) {    // h2 from acc1; writes A1[128+]
    #pragma unroll
    for (int rr = 0; rr < 4; ++rr) {
      const float ig = sigmoid_f(a4[0][rr]);
      const float fg = sigmoid_f(a4[1][rr]);
      const float gg = tanh_f(a4[2][rr]);
      const float og = sigmoid_f(a4[3][rr]);
      const float c  = fmaf(fg, c2[rr], ig * gg);
      c2[rr] = c;
      const float h  = og * tanh_f(c);
      const unsigned short hi = bf16rn(h);
      const unsigned short lo = bf16rn(h - bf16tof(hi));
      const int row = prow + rr;
      A1h[row * S1 + 128 + unit] = hi;  A1l[row * S1 + 128 + unit] = lo;
    }
  };
  auto binit = [&](ffrag a4[4], const float bv[4]) {
    #pragma unroll
    for (int g = 0; g < 4; ++g) a4[g] = (ffrag){bv[g], bv[g], bv[g], bv[g]};
  };
  auto stage_write = [&](float v, int idx) {
    const unsigned short hi = bf16rn(v);
    A0h[idx] = hi;
    A0l[idx] = bf16rn(v - bf16tof(hi));
  };

  __syncthreads();   // zero-fill visible before staging overwrites

  // ---- prologue: stage x(0), compute acc0(0) --------------------------------
  {
    const float* xr = x + ((size_t)(blockIdx.x * BR + xr_row) * T_ + 0) * IN_;
    const float v0 = __builtin_nontemporal_load(xr + xr_col);
    const float v1 = __builtin_nontemporal_load(xr + xr_col + 32);
    float v2 = 0.f;
    if (xr_col < IN_ - 64) v2 = __builtin_nontemporal_load(xr + xr_col + 64);
    stage_write(v0, xr_row * S0 + xr_col);
    stage_write(v1, xr_row * S0 + xr_col + 32);
    if (xr_col < IN_ - 64) stage_write(v2, xr_row * S0 + xr_col + 64);
  }
  bfrag pbp[4];
  load_bk(B0, 0, NT0, wv, lane16, pbp);
  __syncthreads();

  ffrag acc0[4], acc1[4];
  binit(acc0, b0r);
  gemm_seg<0, K0T>(A0h, A0l, a0b, B0, NT0, wv, lane16, pbp, acc0);
  __syncthreads();

  // ---- fused main loop: t = 0..49 (2 barriers per timestep) -----------------
  for (int t = 0; t < T_; ++t) {
    // W phase: issue loads early, then pointwise, then LDS writes.
    bfrag pb1[4], pb0[4];
    load_bk(B1, 0, NT1, wv, lane16, pb1);
    load_bk(B0, 0, NT0, wv, lane16, pb0);
    float v0 = 0.f, v1 = 0.f, v2 = 0.f;
    const bool stg = (t < T_ - 1);         // t=49: u(50)=x(49), already staged
    if (stg) {
      const float* xr = x + ((size_t)(blockIdx.x * BR + xr_row) * T_ + (t + 1)) * IN_;
      v0 = __builtin_nontemporal_load(xr + xr_col);
      v1 = __builtin_nontemporal_load(xr + xr_col + 32);
      if (xr_col < IN_ - 64) v2 = __builtin_nontemporal_load(xr + xr_col + 64);
    }
    if (t > 0) pw_l2(acc1);                // h2(t-1)
    pw_l1(acc0);                           // h1(t)
    if (stg) {
      stage_write(v0, xr_row * S0 + xr_col);
      stage_write(v1, xr_row * S0 + xr_col + 32);
      if (xr_col < IN_ - 64) stage_write(v2, xr_row * S0 + xr_col + 64);
    }
    __syncthreads();   // h1(t), h2(t-1), x(t+1) visible

    // G phase: gates1(t) + gates0(t+1) — independent, one fat phase.
    binit(acc1, b1r);
    gemm_seg<0, K1T>(A1h, A1l, a1b, B1, NT1, wv, lane16, pb1, acc1);
    binit(acc0, b0r);
    gemm_seg<0, K0T>(A0h, A0l, a0b, B0, NT0, wv, lane16, pb0, acc0);
    __syncthreads();   // all reads done before next W overwrites
  }

  // ---- tail: t = 50..64 (pose feedback breaks full fusion) ------------------
  for (int t = T_; t < T_ + NPOSE; ++t) {
    const bool more = (t < T_ + NPOSE - 1);
    // Wa: h1(t) (+ h2(49) once)
    bfrag pb1[4], pb0[4];
    load_bk(B1, 0, NT1, wv, lane16, pb1);
    load_bk(B0, 3, NT0, wv, lane16, pb0);  // partial gates0 starts at ktile 3
    if (t == T_) pw_l2(acc1);              // h2(49)
    pw_l1(acc0);                           // h1(t)
    __syncthreads();

    // Ga: gates1(t) full + gates0(t+1) k-tiles 3..6 (h1-dependent part)
    binit(acc1, b1r);
    gemm_seg<0, K1T>(A1h, A1l, a1b, B1, NT1, wv, lane16, pb1, acc1);
    if (more) {
      binit(acc0, b0r);
      gemm_seg<3, K0T>(A0h, A0l, a0b, B0, NT0, wv, lane16, pb0, acc0);
    }
    __syncthreads();

    // Wb: h2(t)
    pw_l2(acc1);
    __syncthreads();

    // Gb: dense head (waves 0..4) + prefetch Gc's B-frags (all waves)
    bfrag pbg[4];
    if (more) load_bk(B0, 0, NT0, wv, lane16, pbg);
    const int s = t - T_;
    if (wv < NTD) {
      ffrag dacc = (ffrag){bdr, bdr, bdr, bdr};
      #pragma unroll
      for (int k = 0; k < KDT; ++k) {
        const bfrag ah = *(const bfrag*)(A1h + a1b + 128 + k * 32);
        const bfrag al = *(const bfrag*)(A1l + a1b + 128 + k * 32);
        const bfrag bh = *(const bfrag*)(BD + (size_t)(k * NTD + wv) * 1024 + lane16);
        MFMA(dacc, ah, bh);
        MFMA(dacc, al, bh);
      }
      if (od < OUT_) {
        #pragma unroll
        for (int rr = 0; rr < 4; ++rr) {
          const int row = prow + rr;
          const float v = dacc[rr];
          __builtin_nontemporal_store(
              v, out + ((size_t)(blockIdx.x * BR + row) * NPOSE + s) * OUT_ + od);
          if (s < NPOSE - 1) {
            const unsigned short hi = bf16rn(v);
            A0h[row * S0 + od] = hi;
            A0l[row * S0 + od] = bf16rn(v - bf16tof(hi));
          }
        }
      }
    }
    __syncthreads();   // pose visible

    // Gc: gates0(t+1) k-tiles 0..2 (pose|cond region). Reads A0[0..96) only;
    // next Wa writes A0[96+]/A1[0..128) — disjoint, no barrier needed here.
    if (more) {
      gemm_seg<0, 3>(A0h, A0l, a0b, B0, NT0, wv, lane16, pbg, acc0);
    }
  }
}

extern "C" void kernel_launch(void* const* d_in, const int* in_sizes, int n_in,
                              void* d_out, int out_size, void* d_ws, size_t ws_size,
                              hipStream_t stream)
{
  const float* x    = (const float*)d_in[0];
  const float* Wih0 = (const float*)d_in[1];
  const float* Whh0 = (const float*)d_in[2];
  const float* bih0 = (const float*)d_in[3];
  const float* bhh0 = (const float*)d_in[4];
  const float* Wih1 = (const float*)d_in[5];
  const float* Whh1 = (const float*)d_in[6];
  const float* bih1 = (const float*)d_in[7];
  const float* bhh1 = (const float*)d_in[8];
  const float* Wd   = (const float*)d_in[9];
  const float* bd   = (const float*)d_in[10];

  wm_prep<<<(TOT_N + 255) / 256, 256, 0, stream>>>(Wih0, Whh0, Wih1, Whh1, Wd,
                                                   (unsigned short*)d_ws);
  wm_main<<<B_ / BR, 512, 0, stream>>>(x, (const char*)d_ws,
                                       bih0, bhh0, bih1, bhh1, bd,
                                       (float*)d_out);
}

// Round 2
// 1891.329 us; speedup vs baseline: 1.2486x; 1.2486x over previous
//
#include <hip/hip_runtime.h>
#include <hip/hip_bf16.h>
#include <cstdint>
#include <cstddef>

// Problem constants
#define H_    128
#define IN_   86
#define OUT_  66
#define T_    50
#define B_    8192
#define NPOSE 15

// Round-7 design: fusion kept, spills removed, BR=32 weight-amortization.
//  - Round-6 post-mortem: VGPR pinned at 64 while fused loop held pb-prefetch
//    (32 regs) + two accs (32 regs) across barriers -> scratch spills ->
//    FETCH 2.7->5.3GB, WRITE 0.13->0.63GB, dur 1642->2337us. Fix: B-frag
//    loads back inside the k-loop (short liveness), nt hints reverted.
//  - Fusion kept: gates1(t) and gates0(t+1) both depend only on h1(t) ->
//    one fat GEMM phase; main loop = 2 barriers/timestep.
//  - NEW: BR=32, 1024 threads, 16 waves, grid 256 (1 block/CU). Wave pairs
//    (uw, uw+8) own the same unit slice on two 16-row M-tiles: per-CU
//    distinct weight stream per timestep unchanged (491KB) but covers 2x
//    rows -> kernel-total weight traffic through L2/HBM halves.
//  - __launch_bounds__(1024,4): 4 waves/SIMD, VGPR cap 128 (fused state
//    ~60 regs fits, no spill).
// K0 = 224: [u(86)|pad(10)|h1(128)] ; K1 = 256: [h1|h2]
#define K0T 7
#define K1T 8
#define KDT 4
#define NT0 32
#define NT1 32
#define NTD 5
#define S0  232   // A0 row stride (ushorts); 116 dwords = 4*odd (2-way, free)
#define S1  264   // A1 row stride; 132 dwords = 4*odd
#define BR  32
#define THR 1024

// ws layout (bytes) — hi-only packed B fragments
#define B0P_OFF 0
#define B0P_SZ  (K0T * NT0 * 1024)       // 229376
#define B1P_OFF (B0P_OFF + B0P_SZ)
#define B1P_SZ  (K1T * NT1 * 1024)       // 262144
#define BDP_OFF (B1P_OFF + B1P_SZ)       // 491520
#define BDP_SZ  (KDT * NTD * 1024)       // 20480
#define B0P_N (B0P_SZ / 2)               // 114688
#define B1P_N (B1P_SZ / 2)               // 131072
#define TOT_N ((B0P_SZ + B1P_SZ + BDP_SZ) / 2)   // 256000

typedef __attribute__((ext_vector_type(8))) short bfrag;
typedef __attribute__((ext_vector_type(4))) float ffrag;

#define MFMA(AC, AA, BB) \
  AC = __builtin_amdgcn_mfma_f32_16x16x32_bf16((AA), (BB), (AC), 0, 0, 0)

__device__ __forceinline__ unsigned short bf16rn(float f) {
  union { float f; unsigned int u; } cv; cv.f = f;
  unsigned int u = cv.u;
  u += 0x7FFFu + ((u >> 16) & 1u);   // round-to-nearest-even
  return (unsigned short)(u >> 16);
}
__device__ __forceinline__ float bf16tof(unsigned short h) {
  union { unsigned int u; float f; } cv; cv.u = ((unsigned int)h) << 16;
  return cv.f;
}
__device__ __forceinline__ float sigmoid_f(float v) {
  return __fdividef(1.f, 1.f + __expf(-v));
}
__device__ __forceinline__ float tanh_f(float v) {
  float av = fabsf(v);
  float e  = __expf(-2.f * av);
  float t  = __fdividef(1.f - e, 1.f + e);
  return copysignf(t, v);
}

// ---------------- prep: pack hi-only weights in MFMA fragment order ---------
__global__ void wm_prep(
    const float* __restrict__ Wih0, const float* __restrict__ Whh0,
    const float* __restrict__ Wih1, const float* __restrict__ Whh1,
    const float* __restrict__ Wd,
    unsigned short* __restrict__ wsu)
{
  const int idx = blockIdx.x * 256 + threadIdx.x;
  if (idx >= TOT_N) return;
  int region, l;
  if (idx < B0P_N)               { region = 0; l = idx; }
  else if (idx < B0P_N + B1P_N)  { region = 1; l = idx - B0P_N; }
  else                           { region = 2; l = idx - (B0P_N + B1P_N); }

  int k, nt, lane, j;
  if (region < 2) {
    k  = l >> 14;            // 32 tiles * 512 ushorts = 16384 per ktile
    int r1 = l & 16383;
    nt = r1 >> 9;
    int li = r1 & 511;
    lane = li >> 3; j = li & 7;
  } else {
    k  = l / 2560;           // 5 * 512 per ktile
    int r1 = l % 2560;
    nt = r1 >> 9;
    int li = r1 & 511;
    lane = li >> 3; j = li & 7;
  }
  const int n  = nt * 16 + (lane & 15);
  const int kk = k * 32 + (lane >> 4) * 8 + j;

  float v = 0.f;
  if (region == 0) {
    if (kk < IN_)                    v = Wih0[n * IN_ + kk];
    else if (kk >= 96 && kk < 224)   v = Whh0[n * H_ + (kk - 96)];
  } else if (region == 1) {
    v = (kk < H_) ? Wih1[n * H_ + kk] : Whh1[n * H_ + (kk - H_)];
  } else {
    if (n < OUT_)                    v = Wd[n * H_ + kk];
  }
  wsu[idx] = bf16rn(v);
}

// ---------------- GEMM helper: K-tile segment [KF, KL), B loaded in-loop ----
template<int KF, int KL>
__device__ __forceinline__ void gemm_seg(const unsigned short* Ah, const unsigned short* Al,
                                         int ab, const char* __restrict__ Bb, int NT,
                                         int uw, int lane16, ffrag acc[4]) {
  #pragma unroll 2
  for (int k = KF; k < KL; ++k) {
    const bfrag ah = *(const bfrag*)(Ah + ab + k * 32);
    const bfrag al = *(const bfrag*)(Al + ab + k * 32);
    #pragma unroll
    for (int g = 0; g < 4; ++g) {
      const bfrag bh = *(const bfrag*)(Bb + (size_t)(k * NT + g * 8 + uw) * 1024 + lane16);
      MFMA(acc[g], ah, bh);
      MFMA(acc[g], al, bh);
    }
  }
}

// ---------------- main persistent-recurrence kernel --------------------------
__global__ __launch_bounds__(THR, 4) void wm_main(
    const float* __restrict__ x,
    const char*  __restrict__ wsb,
    const float* __restrict__ bih0, const float* __restrict__ bhh0,
    const float* __restrict__ bih1, const float* __restrict__ bhh1,
    const float* __restrict__ bd,
    float* __restrict__ out)
{
  __shared__ __align__(16) unsigned short A0h[BR * S0];
  __shared__ __align__(16) unsigned short A0l[BR * S0];
  __shared__ __align__(16) unsigned short A1h[BR * S1];
  __shared__ __align__(16) unsigned short A1l[BR * S1];

  const int tid  = threadIdx.x;
  const int lane = tid & 63;
  const int wv   = tid >> 6;      // wave id 0..15
  const int uw   = wv & 7;        // unit-slice id (0..7)
  const int mt   = wv >> 3;       // M-tile (0: rows 0..15, 1: rows 16..31)
  const int ln15 = lane & 15;
  const int quad = lane >> 4;
  const int lane16 = lane * 16;

  const char* B0 = wsb + B0P_OFF;
  const char* B1 = wsb + B1P_OFF;
  const char* BD = wsb + BDP_OFF;

  // zero LDS (h/c zero-init; A0 pads [86,96) and [224,232) stay zero)
  for (int i = tid; i < BR * S0; i += THR) { A0h[i] = 0; A0l[i] = 0; }
  for (int i = tid; i < BR * S1; i += THR) { A1h[i] = 0; A1l[i] = 0; }

  // bias preload — this wave's unit col = uw*16 + ln15, per gate g
  float b0r[4], b1r[4];
  #pragma unroll
  for (int g = 0; g < 4; ++g) {
    const int n = g * 128 + uw * 16 + ln15;
    b0r[g] = bih0[n] + bhh0[n];
    b1r[g] = bih1[n] + bhh1[n];
  }
  // dense head: waves with uw<5 own o-tile uw (o = uw*16 + ln15), M-tile mt
  const int od = uw * 16 + ln15;
  const float bdr = (uw < NTD && od < OUT_) ? bd[od] : 0.f;

  float c1[4], c2[4];
  #pragma unroll
  for (int r = 0; r < 4; ++r) { c1[r] = 0.f; c2[r] = 0.f; }

  const int arow = mt * 16 + ln15;         // A-frag source row
  const int a0b  = arow * S0 + quad * 8;
  const int a1b  = arow * S1 + quad * 8;
  const int prow = mt * 16 + quad * 4;     // C/D rows = prow + r
  const int unit = uw * 16 + ln15;         // this lane's unit column
  const int xr_row = tid >> 5;             // staging: 32 rows x 32 lanes
  const int xr_col = tid & 31;

  // pointwise lambdas ---------------------------------------------------------
  auto pw_l1 = [&](const ffrag a4[4]) {    // h1 from acc0; writes A0[96+], A1[0+]
    #pragma unroll
    for (int rr = 0; rr < 4; ++rr) {
      const float ig = sigmoid_f(a4[0][rr]);
      const float fg = sigmoid_f(a4[1][rr]);
      const float gg = tanh_f(a4[2][rr]);
      const float og = sigmoid_f(a4[3][rr]);
      const float c  = fmaf(fg, c1[rr], ig * gg);
      c1[rr] = c;
      const float h  = og * tanh_f(c);
      const unsigned short hi = bf16rn(h);
      const unsigned short lo = bf16rn(h - bf16tof(hi));
      const int row = prow + rr;
      A0h[row * S0 + 96 + unit] = hi;  A0l[row * S0 + 96 + unit] = lo;
      A1h[row * S1 + unit]      = hi;  A1l[row * S1 + unit]      = lo;
    }
  };
  auto pw_l2 = [&](const ffrag a4[4]) {    // h2 from acc1; writes A1[128+]
    #pragma unroll
    for (int rr = 0; rr < 4; ++rr) {
      const float ig = sigmoid_f(a4[0][rr]);
      const float fg = sigmoid_f(a4[1][rr]);
      const float gg = tanh_f(a4[2][rr]);
      const float og = sigmoid_f(a4[3][rr]);
      const float c  = fmaf(fg, c2[rr], ig * gg);
      c2[rr] = c;
      const float h  = og * tanh_f(c);
      const unsigned short hi = bf16rn(h);
      const unsigned short lo = bf16rn(h - bf16tof(hi));
      const int row = prow + rr;
      A1h[row * S1 + 128 + unit] = hi;  A1l[row * S1 + 128 + unit] = lo;
    }
  };
  auto binit = [&](ffrag a4[4], const float bv[4]) {
    #pragma unroll
    for (int g = 0; g < 4; ++g) a4[g] = (ffrag){bv[g], bv[g], bv[g], bv[g]};
  };
  auto stage_write = [&](float v, int idx) {
    const unsigned short hi = bf16rn(v);
    A0h[idx] = hi;
    A0l[idx] = bf16rn(v - bf16tof(hi));
  };

  __syncthreads();   // zero-fill visible before staging overwrites

  // ---- prologue: stage x(0), compute acc0(0) --------------------------------
  {
    const float* xr = x + ((size_t)(blockIdx.x * BR + xr_row) * T_ + 0) * IN_;
    const float v0 = xr[xr_col];
    const float v1 = xr[xr_col + 32];
    float v2 = 0.f;
    if (xr_col < IN_ - 64) v2 = xr[xr_col + 64];
    stage_write(v0, xr_row * S0 + xr_col);
    stage_write(v1, xr_row * S0 + xr_col + 32);
    if (xr_col < IN_ - 64) stage_write(v2, xr_row * S0 + xr_col + 64);
  }
  __syncthreads();

  ffrag acc0[4], acc1[4];
  binit(acc0, b0r);
  gemm_seg<0, K0T>(A0h, A0l, a0b, B0, NT0, uw, lane16, acc0);
  __syncthreads();

  // ---- fused main loop: t = 0..49 (2 barriers per timestep) -----------------
  for (int t = 0; t < T_; ++t) {
    // W phase: x loads issued early, pointwise, LDS writes.
    float v0 = 0.f, v1 = 0.f, v2 = 0.f;
    const bool stg = (t < T_ - 1);         // t=49: u(50)=x(49), already staged
    if (stg) {
      const float* xr = x + ((size_t)(blockIdx.x * BR + xr_row) * T_ + (t + 1)) * IN_;
      v0 = xr[xr_col];
      v1 = xr[xr_col + 32];
      if (xr_col < IN_ - 64) v2 = xr[xr_col + 64];
    }
    if (t > 0) pw_l2(acc1);                // h2(t-1)
    pw_l1(acc0);                           // h1(t)
    if (stg) {
      stage_write(v0, xr_row * S0 + xr_col);
      stage_write(v1, xr_row * S0 + xr_col + 32);
      if (xr_col < IN_ - 64) stage_write(v2, xr_row * S0 + xr_col + 64);
    }
    __syncthreads();   // h1(t), h2(t-1), x(t+1) visible

    // G phase: gates1(t) + gates0(t+1) — independent, one fat phase.
    binit(acc1, b1r);
    gemm_seg<0, K1T>(A1h, A1l, a1b, B1, NT1, uw, lane16, acc1);
    binit(acc0, b0r);
    gemm_seg<0, K0T>(A0h, A0l, a0b, B0, NT0, uw, lane16, acc0);
    __syncthreads();   // all reads done before next W overwrites
  }

  // ---- tail: t = 50..64 (pose feedback breaks full fusion) ------------------
  for (int t = T_; t < T_ + NPOSE; ++t) {
    const bool more = (t < T_ + NPOSE - 1);
    // Wa: h1(t) (+ h2(49) once)
    if (t == T_) pw_l2(acc1);              // h2(49)
    pw_l1(acc0);                           // h1(t)
    __syncthreads();

    // Ga: gates1(t) full + gates0(t+1) k-tiles 3..6 (h1-dependent part)
    binit(acc1, b1r);
    gemm_seg<0, K1T>(A1h, A1l, a1b, B1, NT1, uw, lane16, acc1);
    if (more) {
      binit(acc0, b0r);
      gemm_seg<3, K0T>(A0h, A0l, a0b, B0, NT0, uw, lane16, acc0);
    }
    __syncthreads();

    // Wb: h2(t)
    pw_l2(acc1);
    __syncthreads();

    // Gb: dense head (waves with uw<5, both M-tiles)
    const int s = t - T_;
    if (uw < NTD) {
      ffrag dacc = (ffrag){bdr, bdr, bdr, bdr};
      #pragma unroll
      for (int k = 0; k < KDT; ++k) {
        const bfrag ah = *(const bfrag*)(A1h + a1b + 128 + k * 32);
        const bfrag al = *(const bfrag*)(A1l + a1b + 128 + k * 32);
        const bfrag bh = *(const bfrag*)(BD + (size_t)(k * NTD + uw) * 1024 + lane16);
        MFMA(dacc, ah, bh);
        MFMA(dacc, al, bh);
      }
      if (od < OUT_) {
        #pragma unroll
        for (int rr = 0; rr < 4; ++rr) {
          const int row = prow + rr;
          const float v = dacc[rr];
          out[((size_t)(blockIdx.x * BR + row) * NPOSE + s) * OUT_ + od] = v;
          if (s < NPOSE - 1) {
            const unsigned short hi = bf16rn(v);
            A0h[row * S0 + od] = hi;
            A0l[row * S0 + od] = bf16rn(v - bf16tof(hi));
          }
        }
      }
    }
    __syncthreads();   // pose visible

    // Gc: gates0(t+1) k-tiles 0..2 (pose|cond region). Reads A0[0..96) only;
    // next Wa writes A0[96+]/A1 — disjoint, no barrier needed here.
    if (more) {
      gemm_seg<0, 3>(A0h, A0l, a0b, B0, NT0, uw, lane16, acc0);
    }
  }
}

extern "C" void kernel_launch(void* const* d_in, const int* in_sizes, int n_in,
                              void* d_out, int out_size, void* d_ws, size_t ws_size,
                              hipStream_t stream)
{
  const float* x    = (const float*)d_in[0];
  const float* Wih0 = (const float*)d_in[1];
  const float* Whh0 = (const float*)d_in[2];
  const float* bih0 = (const float*)d_in[3];
  const float* bhh0 = (const float*)d_in[4];
  const float* Wih1 = (const float*)d_in[5];
  const float* Whh1 = (const float*)d_in[6];
  const float* bih1 = (const float*)d_in[7];
  const float* bhh1 = (const float*)d_in[8];
  const float* Wd   = (const float*)d_in[9];
  const float* bd   = (const float*)d_in[10];

  wm_prep<<<(TOT_N + 255) / 256, 256, 0, stream>>>(Wih0, Whh0, Wih1, Whh1, Wd,
                                                   (unsigned short*)d_ws);
  wm_main<<<B_ / BR, THR, 0, stream>>>(x, (const char*)d_ws,
                                       bih0, bhh0, bih1, bhh1, bd,
                                       (float*)d_out);
}